// Round 8
// baseline (109.864 us; speedup 1.0000x reference)
//
#include <hip/hip_runtime.h>

// Problem constants
constexpr int T_    = 4096;
constexpr int DH_   = 128;
constexpr int NB_   = 32;    // buckets
constexpr int BSZ_  = 128;   // bucket size
constexpr int HH_   = 4;     // H/2 (rotated heads start here)
constexpr int H_    = 8;
constexpr int BH_   = 32;    // B*H

typedef __attribute__((ext_vector_type(8))) short short8;
typedef __attribute__((ext_vector_type(4))) float f32x4;
typedef __attribute__((ext_vector_type(4))) unsigned int u32x4;

__device__ __forceinline__ unsigned int cvt_pk_bf16(float lo, float hi) {
  unsigned int r;
  asm("v_cvt_pk_bf16_f32 %0, %1, %2" : "=v"(r) : "v"(lo), "v"(hi));
  return r;
}

// ---------------- Kernel A1: per-bucket column sums + first row of each bucket ----------
__global__ __launch_bounds__(256)
void k_bucket_sums(const float* __restrict__ k,
                   float* __restrict__ bucketsum,
                   float* __restrict__ firstrow) {
  __shared__ float4 red[8][32];
  int blk = blockIdx.x;           // (b*H + h)*NB + u
  int u = blk & (NB_ - 1);
  int bh = blk >> 5;
  int h = bh & (H_ - 1);
  bool rot = (h >= HH_);
  int tid = threadIdx.x;
  int rq = tid >> 5;              // 0..7
  int l  = tid & 31;              // 0..31
  int d0 = l * 4;
  const float* kb = k + (size_t)bh * T_ * DH_;

  float4 s = {0.f, 0.f, 0.f, 0.f};
  float4 first = {0.f, 0.f, 0.f, 0.f};
  #pragma unroll
  for (int it = 0; it < 16; ++it) {
    int i = it * 8 + rq;
    int t = u * BSZ_ + i;
    if (rot) t = (t + (BSZ_ - 1)) & (T_ - 1);
    float4 a = *(const float4*)(kb + (size_t)t * DH_ + d0);
    s.x += a.x; s.y += a.y; s.z += a.z; s.w += a.w;
    if (it == 0 && rq == 0) first = a;
  }
  red[rq][l] = s;
  __syncthreads();
  if (rq == 0) {
    float4 acc = {0.f, 0.f, 0.f, 0.f};
    #pragma unroll
    for (int j = 0; j < 8; ++j) {
      float4 a = red[j][l];
      acc.x += a.x; acc.y += a.y; acc.z += a.z; acc.w += a.w;
    }
    *(float4*)(bucketsum + (size_t)blk * DH_ + d0) = acc;
    *(float4*)(firstrow  + (size_t)blk * DH_ + d0) = first;
  }
}

// ---------------- Kernel A2: routing matrix R -> (scale, idx) packed float2 -------------
__global__ __launch_bounds__(256)
void k_routing(const float* __restrict__ W,
               const float* __restrict__ bucketsum,
               const float* __restrict__ firstrow,
               float2* __restrict__ scIdx) {
  __shared__ float Wl[2 * DH_ * NB_];      // [e][v] row-major, 8192 floats
  __shared__ float Xl[NB_][2 * DH_ + 1];   // padded
  __shared__ float Rl[NB_][36];            // 36-float rows: 16B aligned
  int bh = blockIdx.x;
  int h = bh & (H_ - 1);
  int tid = threadIdx.x;                   // 256 threads

  const float4* Wg = (const float4*)(W + (size_t)h * 2 * DH_ * NB_);
  #pragma unroll
  for (int rep = 0; rep < 8; ++rep)
    ((float4*)Wl)[tid + rep * 256] = Wg[tid + rep * 256];

  if (tid < DH_) {
    int d = tid;
    float S = 0.f;
    for (int u = 0; u < NB_; ++u) {
      float fr = firstrow [((size_t)bh * NB_ + u) * DH_ + d];
      float bs = bucketsum[((size_t)bh * NB_ + u) * DH_ + d];
      Xl[u][d]        = (S + fr) / (float)(u * BSZ_ + 1);
      Xl[u][DH_ + d]  = fr;
      S += bs;
    }
  }
  __syncthreads();

  {
    int u = tid >> 3;
    int vg = tid & 7;
    float4 racc = {0.f, 0.f, 0.f, 0.f};
    for (int e = 0; e < 2 * DH_; ++e) {
      float xv = Xl[u][e];
      float4 wv = *(const float4*)(Wl + e * NB_ + vg * 4);
      racc.x += xv * wv.x; racc.y += xv * wv.y;
      racc.z += xv * wv.z; racc.w += xv * wv.w;
    }
    racc.x = (racc.x > 0.f) ? racc.x : 0.01f * racc.x;
    racc.y = (racc.y > 0.f) ? racc.y : 0.01f * racc.y;
    racc.z = (racc.z > 0.f) ? racc.z : 0.01f * racc.z;
    racc.w = (racc.w > 0.f) ? racc.w : 0.01f * racc.w;
    *(float4*)(&Rl[u][vg * 4]) = racc;
  }
  __syncthreads();

  if (tid < NB_) {
    int u = tid;
    float m = -3.4e38f;
    float r[NB_];
    #pragma unroll
    for (int v = 0; v < NB_; ++v) { r[v] = Rl[u][v]; m = fmaxf(m, r[v]); }
    float Z = 0.f;
    #pragma unroll
    for (int v = 0; v < NB_; ++v) Z += expf(r[v] - m);
    float best = -3.4e38f; int bi = 0;
    for (int v = 0; v < u; ++v) {        // tril(-1): only v < u survive
      if (r[v] > best) { best = r[v]; bi = v; }
    }
    float sc = (u == 0) ? 0.f : expf(best - m) / Z;
    int  idx = (u == 0) ? 0 : bi;
    scIdx[bh * NB_ + u] = make_float2(sc, __int_as_float(idx));
  }
}

// ---------------- Kernel B: online-softmax halves, register P (union-free packs) -------
// RA 32KB: K1(src) -> VT1(src). RB 32KB: K2(own) -> VT2(own).
// acc is 32 f32 (one j-half at a time); P halves packed bf16 with flash combine.
__global__ __launch_bounds__(512, 4)
void k_attn(const float* __restrict__ q, const float* __restrict__ k,
            const float* __restrict__ v, const float2* __restrict__ scIdx,
            float* __restrict__ out) {
  __shared__ __align__(16) unsigned short RA[128 * 128];   // 32KB
  __shared__ __align__(16) unsigned short RB[128 * 128];   // 32KB

  int blk0 = blockIdx.x;
  int blk  = ((blk0 & 7) << 7) | (blk0 >> 3);  // XCD-chunked swizzle (1024 = 8*128)
  int u  = blk & (NB_ - 1);
  int bh = blk >> 5;
  int h  = bh & (H_ - 1);
  bool rot = (h >= HH_);
  float2 si = scIdx[bh * NB_ + u];
  float sc = si.x;
  int  src = __float_as_int(si.y);
  const size_t base = (size_t)bh * T_ * DH_;

  int tid  = threadIdx.x;
  int lane = tid & 63;
  int w    = tid >> 6;        // wave 0..7, owns q-rows [16w, 16w+16)
  int g    = lane >> 4;       // 0..3
  int c    = lane & 15;       // 0..15

  // ---- Q fragments (B-operand: col = c -> i = 16w + c) ----
  short8 qf[4];
  {
    int t = u * BSZ_ + 16 * w + c;
    if (rot) t = (t + (BSZ_ - 1)) & (T_ - 1);
    const float* qrow = q + base + (size_t)t * DH_;
    #pragma unroll
    for (int kt = 0; kt < 4; ++kt) {
      f32x4 a = *(const f32x4*)(qrow + kt * 32 + g * 8);
      f32x4 b = *(const f32x4*)(qrow + kt * 32 + g * 8 + 4);
      u32x4 tt;
      tt.x = cvt_pk_bf16(a[0], a[1]);
      tt.y = cvt_pk_bf16(a[2], a[3]);
      tt.z = cvt_pk_bf16(b[0], b[1]);
      tt.w = cvt_pk_bf16(b[2], b[3]);
      qf[kt] = __builtin_bit_cast(short8, tt);
    }
  }

  // ---- Stage K halves (pure copy-convert): K1->RA, K2->RB ----
  #pragma unroll
  for (int rep = 0; rep < 16; ++rep) {
    int chunk = tid + rep * 512;          // 8192 chunks of 4 floats
    int jr = chunk >> 5;                  // 0..255
    int c0 = (chunk & 31) * 4;
    int t = (jr < BSZ_) ? (src * BSZ_ + jr) : (u * BSZ_ + (jr - BSZ_));
    if (rot) t = (t + (BSZ_ - 1)) & (T_ - 1);
    f32x4 a = *(const f32x4*)(k + base + (size_t)t * DH_ + c0);
    uint2 wv;
    wv.x = cvt_pk_bf16(a[0], a[1]);
    wv.y = cvt_pk_bf16(a[2], a[3]);
    unsigned short* Rg = (jr < BSZ_) ? RA : RB;
    int row = jr & 127;
    *(uint2*)((char*)Rg + row * 256 + ((c0 * 2) ^ ((row & 15) << 4))) = wv;
  }
  __syncthreads();   // S1

  // ---- VT staging helper: load -> convert -> commit (transient regs only) ----
  // Column permute within each 32-j block: jc = (j&~31) | 8*((j>>2)&3) | 4*((j>>4)&1) | (j&3)
  auto vt_stage = [&](int sb, unsigned short* Rg) {
    #pragma unroll
    for (int rep = 0; rep < 2; ++rep) {
      int j0 = ((tid >> 5) + rep * 16) * 4;
      int jc0 = (j0 & ~31) | (((j0 >> 2) & 3) << 3) | (((j0 >> 4) & 1) << 2);
      int d0 = (tid & 31) * 4;
      f32x4 rr[4];
      #pragma unroll
      for (int jj = 0; jj < 4; ++jj) {
        int t = sb * BSZ_ + j0 + jj;
        if (rot) t = (t + (BSZ_ - 1)) & (T_ - 1);
        rr[jj] = *(const f32x4*)(v + base + (size_t)t * DH_ + d0);
      }
      #pragma unroll
      for (int m = 0; m < 4; ++m) {
        uint2 wv;
        wv.x = cvt_pk_bf16(rr[0][m], rr[1][m]);
        wv.y = cvt_pk_bf16(rr[2][m], rr[3][m]);
        int row = d0 + m;
        *(uint2*)((char*)Rg + row * 256 + ((jc0 * 2) ^ ((row & 15) << 4))) = wv;
      }
    }
  };

  const bool lastrot = rot && (u == NB_ - 1);
  const float LOG2E = 1.44269504f;
  const float scale1 = 0.03125f * LOG2E * sc;   // half1 (src bucket) score scale
  const float scale2 = 0.03125f * LOG2E;        // half2 (own bucket)
  const int i = 16 * w + c;
  const bool killLow = lastrot && (i > 0);

  // ---- QK half1 (RA): acc[jt][r] = S[j=16jt+4g+r][i=16w+c] ----
  f32x4 acc[8];
  #pragma unroll
  for (int jt = 0; jt < 8; ++jt) acc[jt] = f32x4{0.f, 0.f, 0.f, 0.f};
  __builtin_amdgcn_s_setprio(1);
  #pragma unroll
  for (int kt = 0; kt < 4; ++kt) {
    #pragma unroll
    for (int jt = 0; jt < 8; ++jt) {
      int row = jt * 16 + c;
      short8 bfr = *(const short8*)((const char*)RA + row * 256 + ((kt * 64 + g * 16) ^ ((row & 15) << 4)));
      acc[jt] = __builtin_amdgcn_mfma_f32_16x16x32_bf16(bfr, qf[kt], acc[jt], 0, 0, 0);
    }
  }
  __builtin_amdgcn_s_setprio(0);
  __syncthreads();   // S2a (QK1 reads done; RA free)

  vt_stage(src, RA);           // VT1 -> RA; loads hide under sm1 + QK2

  // ---- softmax stage 1: stats + pack P1 (unnormalized, <=1) ----
  float m1 = -3.4e38f;
  #pragma unroll
  for (int jt = 0; jt < 8; ++jt) {
    #pragma unroll
    for (int r = 0; r < 4; ++r) {
      float s = acc[jt][r] * scale1;
      s = killLow ? -3.4e38f : s;
      acc[jt][r] = s;
      m1 = fmaxf(m1, s);
    }
  }
  m1 = fmaxf(m1, __shfl_xor(m1, 16));
  m1 = fmaxf(m1, __shfl_xor(m1, 32));
  float z1 = 0.f;
  #pragma unroll
  for (int jt = 0; jt < 8; ++jt) {
    #pragma unroll
    for (int r = 0; r < 4; ++r) {
      float p = exp2f(acc[jt][r] - m1);
      acc[jt][r] = p;
      z1 += p;
    }
  }
  z1 += __shfl_xor(z1, 16);
  z1 += __shfl_xor(z1, 32);

  short8 pa1[4];
  #pragma unroll
  for (int m = 0; m < 4; ++m) {
    u32x4 tt;
    tt.x = cvt_pk_bf16(acc[2 * m][0],     acc[2 * m][1]);
    tt.y = cvt_pk_bf16(acc[2 * m][2],     acc[2 * m][3]);
    tt.z = cvt_pk_bf16(acc[2 * m + 1][0], acc[2 * m + 1][1]);
    tt.w = cvt_pk_bf16(acc[2 * m + 1][2], acc[2 * m + 1][3]);
    pa1[m] = __builtin_bit_cast(short8, tt);
  }

  // ---- QK half2 (RB), reusing acc ----
  #pragma unroll
  for (int jt = 0; jt < 8; ++jt) acc[jt] = f32x4{0.f, 0.f, 0.f, 0.f};
  __builtin_amdgcn_s_setprio(1);
  #pragma unroll
  for (int kt = 0; kt < 4; ++kt) {
    #pragma unroll
    for (int jt = 0; jt < 8; ++jt) {
      int row = jt * 16 + c;
      short8 bfr = *(const short8*)((const char*)RB + row * 256 + ((kt * 64 + g * 16) ^ ((row & 15) << 4)));
      acc[jt] = __builtin_amdgcn_mfma_f32_16x16x32_bf16(bfr, qf[kt], acc[jt], 0, 0, 0);
    }
  }
  __builtin_amdgcn_s_setprio(0);

  // ---- softmax stage 2 + flash combine ----
  float m2 = -3.4e38f;
  #pragma unroll
  for (int jt = 0; jt < 8; ++jt) {
    #pragma unroll
    for (int r = 0; r < 4; ++r) {
      int jb = 16 * jt + 4 * g + r;
      float s = acc[jt][r] * scale2;
      bool vis = (i >= jb);
      if (jt == 0) vis = vis && !(killLow && (g == 0) && (r == 0));
      s = vis ? s : -3.4e38f;
      acc[jt][r] = s;
      m2 = fmaxf(m2, s);
    }
  }
  m2 = fmaxf(m2, __shfl_xor(m2, 16));
  m2 = fmaxf(m2, __shfl_xor(m2, 32));
  float z2 = 0.f;
  #pragma unroll
  for (int jt = 0; jt < 8; ++jt) {
    #pragma unroll
    for (int r = 0; r < 4; ++r) {
      float p = exp2f(acc[jt][r] - m2);
      acc[jt][r] = p;
      z2 += p;
    }
  }
  z2 += __shfl_xor(z2, 16);
  z2 += __shfl_xor(z2, 32);

  float mfull = fmaxf(m1, m2);
  float e1 = exp2f(m1 - mfull);
  float e2 = exp2f(m2 - mfull);
  float z  = z1 * e1 + z2 * e2;
  float rz = 1.f / z;
  float f1 = sc * e1 * rz;      // rescale for PV1 contribution (per softmax-row, lane-local)
  float f2 = e2 * rz;           // folded into PA2 values

  short8 pa2[4];
  #pragma unroll
  for (int m = 0; m < 4; ++m) {
    u32x4 tt;
    tt.x = cvt_pk_bf16(acc[2 * m][0] * f2,     acc[2 * m][1] * f2);
    tt.y = cvt_pk_bf16(acc[2 * m][2] * f2,     acc[2 * m][3] * f2);
    tt.z = cvt_pk_bf16(acc[2 * m + 1][0] * f2, acc[2 * m + 1][1] * f2);
    tt.w = cvt_pk_bf16(acc[2 * m + 1][2] * f2, acc[2 * m + 1][3] * f2);
    pa2[m] = __builtin_bit_cast(short8, tt);
  }
  __syncthreads();   // S2b (QK2 reads of RB done)

  vt_stage(u, RB);             // VT2 -> RB
  __syncthreads();   // S3

  // ---- PV1 (RA) -> per-row rescale -> PV2 (RB) ----
  f32x4 o[8];
  #pragma unroll
  for (int nt = 0; nt < 8; ++nt) o[nt] = f32x4{0.f, 0.f, 0.f, 0.f};

  __builtin_amdgcn_s_setprio(1);
  #pragma unroll
  for (int m = 0; m < 4; ++m) {
    #pragma unroll
    for (int nt = 0; nt < 8; ++nt) {
      int vrow = nt * 16 + c;
      short8 vb = *(const short8*)((const char*)RA + vrow * 256 + ((m * 64 + g * 16) ^ ((vrow & 15) << 4)));
      o[nt] = __builtin_amdgcn_mfma_f32_16x16x32_bf16(pa1[m], vb, o[nt], 0, 0, 0);
    }
  }
  __builtin_amdgcn_s_setprio(0);

  #pragma unroll
  for (int r = 0; r < 4; ++r) {
    float fr = __shfl(f1, 4 * g + r);   // factor for output row i' = 16w + 4g + r
    #pragma unroll
    for (int nt = 0; nt < 8; ++nt) o[nt][r] *= fr;
  }

  __builtin_amdgcn_s_setprio(1);
  #pragma unroll
  for (int m = 0; m < 4; ++m) {
    #pragma unroll
    for (int nt = 0; nt < 8; ++nt) {
      int vrow = nt * 16 + c;
      short8 vb = *(const short8*)((const char*)RB + vrow * 256 + ((m * 64 + g * 16) ^ ((vrow & 15) << 4)));
      o[nt] = __builtin_amdgcn_mfma_f32_16x16x32_bf16(pa2[m], vb, o[nt], 0, 0, 0);
    }
  }
  __builtin_amdgcn_s_setprio(0);

  // ---- store (undo rotation); o[nt][r] = O[i=16w+4g+r][d=16nt+c], already normalized ----
  #pragma unroll
  for (int r = 0; r < 4; ++r) {
    int il = 4 * g + r;
    int t = u * BSZ_ + 16 * w + il;
    if (rot) t = (t + (BSZ_ - 1)) & (T_ - 1);
    float* orow = out + base + (size_t)t * DH_;
    #pragma unroll
    for (int nt = 0; nt < 8; ++nt) {
      orow[nt * 16 + c] = o[nt][r];
    }
  }
}

extern "C" void kernel_launch(void* const* d_in, const int* in_sizes, int n_in,
                              void* d_out, int out_size, void* d_ws, size_t ws_size,
                              hipStream_t stream) {
  const float* q = (const float*)d_in[0];
  const float* k = (const float*)d_in[1];
  const float* v = (const float*)d_in[2];
  const float* W = (const float*)d_in[3];
  float* out = (float*)d_out;

  float*  bucketsum = (float*)d_ws;                 // 131072 floats
  float*  firstrow  = bucketsum + 131072;           // 131072 floats
  float2* scIdx     = (float2*)(firstrow + 131072); // 1024 float2

  k_bucket_sums<<<BH_ * NB_, 256, 0, stream>>>(k, bucketsum, firstrow);
  k_routing<<<BH_, 256, 0, stream>>>(W, bucketsum, firstrow, scIdx);
  k_attn<<<BH_ * NB_, 512, 0, stream>>>(q, k, v, scIdx, out);
}

// Round 9
// 94.041 us; speedup vs baseline: 1.1682x; 1.1682x over previous
//
#include <hip/hip_runtime.h>

// Problem constants
constexpr int T_    = 4096;
constexpr int DH_   = 128;
constexpr int NB_   = 32;    // buckets
constexpr int BSZ_  = 128;   // bucket size
constexpr int HH_   = 4;     // H/2 (rotated heads start here)
constexpr int H_    = 8;
constexpr int BH_   = 32;    // B*H

typedef __attribute__((ext_vector_type(8))) short short8;
typedef __attribute__((ext_vector_type(4))) float f32x4;
typedef __attribute__((ext_vector_type(4))) unsigned int u32x4;

__device__ __forceinline__ unsigned int cvt_pk_bf16(float lo, float hi) {
  unsigned int r;
  asm("v_cvt_pk_bf16_f32 %0, %1, %2" : "=v"(r) : "v"(lo), "v"(hi));
  return r;
}

// ---------------- Kernel A1: per-bucket column sums + first row of each bucket ----------
__global__ __launch_bounds__(256)
void k_bucket_sums(const float* __restrict__ k,
                   float* __restrict__ bucketsum,
                   float* __restrict__ firstrow) {
  __shared__ float4 red[8][32];
  int blk = blockIdx.x;           // (b*H + h)*NB + u
  int u = blk & (NB_ - 1);
  int bh = blk >> 5;
  int h = bh & (H_ - 1);
  bool rot = (h >= HH_);
  int tid = threadIdx.x;
  int rq = tid >> 5;              // 0..7
  int l  = tid & 31;              // 0..31
  int d0 = l * 4;
  const float* kb = k + (size_t)bh * T_ * DH_;

  float4 s = {0.f, 0.f, 0.f, 0.f};
  float4 first = {0.f, 0.f, 0.f, 0.f};
  #pragma unroll
  for (int it = 0; it < 16; ++it) {
    int i = it * 8 + rq;
    int t = u * BSZ_ + i;
    if (rot) t = (t + (BSZ_ - 1)) & (T_ - 1);
    float4 a = *(const float4*)(kb + (size_t)t * DH_ + d0);
    s.x += a.x; s.y += a.y; s.z += a.z; s.w += a.w;
    if (it == 0 && rq == 0) first = a;
  }
  red[rq][l] = s;
  __syncthreads();
  if (rq == 0) {
    float4 acc = {0.f, 0.f, 0.f, 0.f};
    #pragma unroll
    for (int j = 0; j < 8; ++j) {
      float4 a = red[j][l];
      acc.x += a.x; acc.y += a.y; acc.z += a.z; acc.w += a.w;
    }
    *(float4*)(bucketsum + (size_t)blk * DH_ + d0) = acc;
    *(float4*)(firstrow  + (size_t)blk * DH_ + d0) = first;
  }
}

// ---------------- Kernel A2: routing matrix R -> (scale, idx) packed float2 -------------
__global__ __launch_bounds__(256)
void k_routing(const float* __restrict__ W,
               const float* __restrict__ bucketsum,
               const float* __restrict__ firstrow,
               float2* __restrict__ scIdx) {
  __shared__ float Wl[2 * DH_ * NB_];      // [e][v] row-major, 8192 floats
  __shared__ float Xl[NB_][2 * DH_ + 1];   // padded
  __shared__ float Rl[NB_][36];            // 36-float rows: 16B aligned
  int bh = blockIdx.x;
  int h = bh & (H_ - 1);
  int tid = threadIdx.x;                   // 256 threads

  const float4* Wg = (const float4*)(W + (size_t)h * 2 * DH_ * NB_);
  #pragma unroll
  for (int rep = 0; rep < 8; ++rep)
    ((float4*)Wl)[tid + rep * 256] = Wg[tid + rep * 256];

  if (tid < DH_) {
    int d = tid;
    float S = 0.f;
    for (int u = 0; u < NB_; ++u) {
      float fr = firstrow [((size_t)bh * NB_ + u) * DH_ + d];
      float bs = bucketsum[((size_t)bh * NB_ + u) * DH_ + d];
      Xl[u][d]        = (S + fr) / (float)(u * BSZ_ + 1);
      Xl[u][DH_ + d]  = fr;
      S += bs;
    }
  }
  __syncthreads();

  {
    int u = tid >> 3;
    int vg = tid & 7;
    float4 racc = {0.f, 0.f, 0.f, 0.f};
    for (int e = 0; e < 2 * DH_; ++e) {
      float xv = Xl[u][e];
      float4 wv = *(const float4*)(Wl + e * NB_ + vg * 4);
      racc.x += xv * wv.x; racc.y += xv * wv.y;
      racc.z += xv * wv.z; racc.w += xv * wv.w;
    }
    racc.x = (racc.x > 0.f) ? racc.x : 0.01f * racc.x;
    racc.y = (racc.y > 0.f) ? racc.y : 0.01f * racc.y;
    racc.z = (racc.z > 0.f) ? racc.z : 0.01f * racc.z;
    racc.w = (racc.w > 0.f) ? racc.w : 0.01f * racc.w;
    *(float4*)(&Rl[u][vg * 4]) = racc;
  }
  __syncthreads();

  if (tid < NB_) {
    int u = tid;
    float m = -3.4e38f;
    float r[NB_];
    #pragma unroll
    for (int v = 0; v < NB_; ++v) { r[v] = Rl[u][v]; m = fmaxf(m, r[v]); }
    float Z = 0.f;
    #pragma unroll
    for (int v = 0; v < NB_; ++v) Z += expf(r[v] - m);
    float best = -3.4e38f; int bi = 0;
    for (int v = 0; v < u; ++v) {        // tril(-1): only v < u survive
      if (r[v] > best) { best = r[v]; bi = v; }
    }
    float sc = (u == 0) ? 0.f : expf(best - m) / Z;
    int  idx = (u == 0) ? 0 : bi;
    scIdx[bh * NB_ + u] = make_float2(sc, __int_as_float(idx));
  }
}

// ---------------- Kernel B: R6 structure + async-STAGE split for V (T14) ---------------
// RA 32KB: K1(src) -> VT1(src). RB 32KB: K2(own) -> VT2(own).
// V1 loads issued post-QK (qf dead), committed after S2; V2 loads issued after V1 commit,
// latency hidden under softmax, committed after the P pack (acc dead).
__global__ __launch_bounds__(512, 4)
void k_attn(const float* __restrict__ q, const float* __restrict__ k,
            const float* __restrict__ v, const float2* __restrict__ scIdx,
            float* __restrict__ out) {
  __shared__ __align__(16) unsigned short RA[128 * 128];   // 32KB
  __shared__ __align__(16) unsigned short RB[128 * 128];   // 32KB

  int blk0 = blockIdx.x;
  int blk  = ((blk0 & 7) << 7) | (blk0 >> 3);  // XCD-chunked swizzle (1024 = 8*128)
  int u  = blk & (NB_ - 1);
  int bh = blk >> 5;
  int h  = bh & (H_ - 1);
  bool rot = (h >= HH_);
  float2 si = scIdx[bh * NB_ + u];
  float sc = si.x;
  int  src = __float_as_int(si.y);
  const size_t base = (size_t)bh * T_ * DH_;

  int tid  = threadIdx.x;
  int lane = tid & 63;
  int w    = tid >> 6;        // wave 0..7, owns q-rows [16w, 16w+16)
  int g    = lane >> 4;       // 0..3
  int c    = lane & 15;       // 0..15

  // ---- Q fragments (B-operand: col = c -> i = 16w + c) ----
  short8 qf[4];
  {
    int t = u * BSZ_ + 16 * w + c;
    if (rot) t = (t + (BSZ_ - 1)) & (T_ - 1);
    const float* qrow = q + base + (size_t)t * DH_;
    #pragma unroll
    for (int kt = 0; kt < 4; ++kt) {
      f32x4 a = *(const f32x4*)(qrow + kt * 32 + g * 8);
      f32x4 b = *(const f32x4*)(qrow + kt * 32 + g * 8 + 4);
      u32x4 tt;
      tt.x = cvt_pk_bf16(a[0], a[1]);
      tt.y = cvt_pk_bf16(a[2], a[3]);
      tt.z = cvt_pk_bf16(b[0], b[1]);
      tt.w = cvt_pk_bf16(b[2], b[3]);
      qf[kt] = __builtin_bit_cast(short8, tt);
    }
  }

  // ---- Stage K halves (pure copy-convert): K1->RA, K2->RB ----
  #pragma unroll
  for (int rep = 0; rep < 16; ++rep) {
    int chunk = tid + rep * 512;          // 8192 chunks of 4 floats
    int jr = chunk >> 5;                  // 0..255
    int c0 = (chunk & 31) * 4;
    int t = (jr < BSZ_) ? (src * BSZ_ + jr) : (u * BSZ_ + (jr - BSZ_));
    if (rot) t = (t + (BSZ_ - 1)) & (T_ - 1);
    f32x4 a = *(const f32x4*)(k + base + (size_t)t * DH_ + c0);
    uint2 wv;
    wv.x = cvt_pk_bf16(a[0], a[1]);
    wv.y = cvt_pk_bf16(a[2], a[3]);
    unsigned short* Rg = (jr < BSZ_) ? RA : RB;
    int row = jr & 127;
    *(uint2*)((char*)Rg + row * 256 + ((c0 * 2) ^ ((row & 15) << 4))) = wv;
  }
  __syncthreads();   // S1

  // ---- VT issue/commit helpers (async-STAGE split; all indices compile-time) ----
  // Column permute within each 32-j block: jc = (j&~31) | 8*((j>>2)&3) | 4*((j>>4)&1) | (j&3)
  auto vt_issue = [&](int sb, f32x4* rr) {
    #pragma unroll
    for (int rep = 0; rep < 2; ++rep) {
      int j0 = ((tid >> 5) + rep * 16) * 4;
      int d0 = (tid & 31) * 4;
      #pragma unroll
      for (int jj = 0; jj < 4; ++jj) {
        int t = sb * BSZ_ + j0 + jj;
        if (rot) t = (t + (BSZ_ - 1)) & (T_ - 1);
        rr[rep * 4 + jj] = *(const f32x4*)(v + base + (size_t)t * DH_ + d0);
      }
    }
  };
  auto vt_commit = [&](const f32x4* rr, unsigned short* Rg) {
    #pragma unroll
    for (int rep = 0; rep < 2; ++rep) {
      int j0 = ((tid >> 5) + rep * 16) * 4;
      int jc0 = (j0 & ~31) | (((j0 >> 2) & 3) << 3) | (((j0 >> 4) & 1) << 2);
      int d0 = (tid & 31) * 4;
      #pragma unroll
      for (int m = 0; m < 4; ++m) {
        uint2 wv;
        wv.x = cvt_pk_bf16(rr[rep * 4 + 0][m], rr[rep * 4 + 1][m]);
        wv.y = cvt_pk_bf16(rr[rep * 4 + 2][m], rr[rep * 4 + 3][m]);
        int row = d0 + m;
        *(uint2*)((char*)Rg + row * 256 + ((jc0 * 2) ^ ((row & 15) << 4))) = wv;
      }
    }
  };

  // ---- QK^T swapped: acc[jt][r] = S[j = 16jt+4g+r][i = 16w+c] ----
  f32x4 acc[16];
  #pragma unroll
  for (int jt = 0; jt < 16; ++jt) acc[jt] = f32x4{0.f, 0.f, 0.f, 0.f};

  __builtin_amdgcn_s_setprio(1);
  #pragma unroll
  for (int kt = 0; kt < 4; ++kt) {
    #pragma unroll
    for (int jt = 0; jt < 16; ++jt) {
      const unsigned short* Rg = (jt < 8) ? RA : RB;
      int row = (jt & 7) * 16 + c;
      short8 bfr = *(const short8*)((const char*)Rg + row * 256 + ((kt * 64 + g * 16) ^ ((row & 15) << 4)));
      acc[jt] = __builtin_amdgcn_mfma_f32_16x16x32_bf16(bfr, qf[kt], acc[jt], 0, 0, 0);
    }
  }
  __builtin_amdgcn_s_setprio(0);

  f32x4 vr[8];
  vt_issue(src, vr);           // V1 loads in flight across S2 (qf dead, acc live: ~111 regs)

  __syncthreads();   // S2 (K reads done; RA/RB free)

  vt_commit(vr, RA);           // VT1 -> RA
  vt_issue(u, vr);             // V2 loads; latency hides under softmax

  // ---- mask + softmax, fully lane-local row (i = 16w + c) ----
  const bool lastrot = rot && (u == NB_ - 1);
  const float LOG2E = 1.44269504f;
  float scale1 = 0.03125f * LOG2E * sc;   // cols j<128 (src bucket)
  float scale2 = 0.03125f * LOG2E;        // cols j>=128 (own bucket)
  const int i = 16 * w + c;
  const bool killLow = lastrot && (i > 0);

  float mx = -3.4e38f;
  #pragma unroll
  for (int jt = 0; jt < 16; ++jt) {
    #pragma unroll
    for (int r = 0; r < 4; ++r) {
      float s = acc[jt][r] * ((jt < 8) ? scale1 : scale2);
      bool vis;
      if (jt < 8) {
        vis = !killLow;
      } else {
        int jb = 16 * (jt - 8) + 4 * g + r;
        vis = (i >= jb);
        if (jt == 8) vis = vis && !(killLow && (g == 0) && (r == 0));
      }
      s = vis ? s : -3.4e38f;
      acc[jt][r] = s;
      mx = fmaxf(mx, s);
    }
  }
  mx = fmaxf(mx, __shfl_xor(mx, 16));
  mx = fmaxf(mx, __shfl_xor(mx, 32));
  float zs = 0.f;
  #pragma unroll
  for (int jt = 0; jt < 16; ++jt) {
    #pragma unroll
    for (int r = 0; r < 4; ++r) {
      float p = exp2f(acc[jt][r] - mx);
      acc[jt][r] = p;
      zs += p;
    }
  }
  zs += __shfl_xor(zs, 16);
  zs += __shfl_xor(zs, 32);
  float rz = 1.f / zs;
  float rzs = rz * sc;                   // P cols j<128 carry sc into PV
  #pragma unroll
  for (int jt = 0; jt < 16; ++jt) {
    #pragma unroll
    for (int r = 0; r < 4; ++r) acc[jt][r] *= (jt < 8) ? rzs : rz;
  }

  // ---- P A-frags: pure register repack (matches VT column permute); acc dies here ----
  short8 pa[8];
  #pragma unroll
  for (int m = 0; m < 8; ++m) {
    u32x4 tt;
    tt.x = cvt_pk_bf16(acc[2 * m][0],     acc[2 * m][1]);
    tt.y = cvt_pk_bf16(acc[2 * m][2],     acc[2 * m][3]);
    tt.z = cvt_pk_bf16(acc[2 * m + 1][0], acc[2 * m + 1][1]);
    tt.w = cvt_pk_bf16(acc[2 * m + 1][2], acc[2 * m + 1][3]);
    pa[m] = __builtin_bit_cast(short8, tt);
  }

  vt_commit(vr, RB);           // VT2 -> RB (loads arrived during softmax)
  __syncthreads();   // S3

  // ---- PV: one contiguous 64-MFMA cluster, P from registers ----
  f32x4 o[8];
  #pragma unroll
  for (int nt = 0; nt < 8; ++nt) o[nt] = f32x4{0.f, 0.f, 0.f, 0.f};

  __builtin_amdgcn_s_setprio(1);
  #pragma unroll
  for (int m = 0; m < 8; ++m) {
    const unsigned short* Rg = (m < 4) ? RA : RB;
    int mloc = m & 3;
    #pragma unroll
    for (int nt = 0; nt < 8; ++nt) {
      int vrow = nt * 16 + c;
      short8 vb = *(const short8*)((const char*)Rg + vrow * 256 + ((mloc * 64 + g * 16) ^ ((vrow & 15) << 4)));
      o[nt] = __builtin_amdgcn_mfma_f32_16x16x32_bf16(pa[m], vb, o[nt], 0, 0, 0);
    }
  }
  __builtin_amdgcn_s_setprio(0);

  // ---- store (undo rotation); o[nt][r] = O[i=16w+4g+r][d=16nt+c] ----
  #pragma unroll
  for (int r = 0; r < 4; ++r) {
    int il = 4 * g + r;
    int t = u * BSZ_ + 16 * w + il;
    if (rot) t = (t + (BSZ_ - 1)) & (T_ - 1);
    float* orow = out + base + (size_t)t * DH_;
    #pragma unroll
    for (int nt = 0; nt < 8; ++nt) {
      orow[nt * 16 + c] = o[nt][r];
    }
  }
}

extern "C" void kernel_launch(void* const* d_in, const int* in_sizes, int n_in,
                              void* d_out, int out_size, void* d_ws, size_t ws_size,
                              hipStream_t stream) {
  const float* q = (const float*)d_in[0];
  const float* k = (const float*)d_in[1];
  const float* v = (const float*)d_in[2];
  const float* W = (const float*)d_in[3];
  float* out = (float*)d_out;

  float*  bucketsum = (float*)d_ws;                 // 131072 floats
  float*  firstrow  = bucketsum + 131072;           // 131072 floats
  float2* scIdx     = (float2*)(firstrow + 131072); // 1024 float2

  k_bucket_sums<<<BH_ * NB_, 256, 0, stream>>>(k, bucketsum, firstrow);
  k_routing<<<BH_, 256, 0, stream>>>(W, bucketsum, firstrow, scIdx);
  k_attn<<<BH_ * NB_, 512, 0, stream>>>(q, k, v, scIdx, out);
}

// Round 10
// 92.429 us; speedup vs baseline: 1.1886x; 1.0174x over previous
//
#include <hip/hip_runtime.h>

// Problem constants
constexpr int T_    = 4096;
constexpr int DH_   = 128;
constexpr int NB_   = 32;    // buckets
constexpr int BSZ_  = 128;   // bucket size
constexpr int HH_   = 4;     // H/2 (rotated heads start here)
constexpr int H_    = 8;
constexpr int BH_   = 32;    // B*H

typedef __attribute__((ext_vector_type(8))) short short8;
typedef __attribute__((ext_vector_type(4))) float f32x4;
typedef __attribute__((ext_vector_type(4))) unsigned int u32x4;

__device__ __forceinline__ unsigned int cvt_pk_bf16(float lo, float hi) {
  unsigned int r;
  asm("v_cvt_pk_bf16_f32 %0, %1, %2" : "=v"(r) : "v"(lo), "v"(hi));
  return r;
}

// ---------------- Kernel A1: per-bucket column sums + first row of each bucket ----------
__global__ __launch_bounds__(256)
void k_bucket_sums(const float* __restrict__ k,
                   float* __restrict__ bucketsum,
                   float* __restrict__ firstrow) {
  __shared__ float4 red[8][32];
  int blk = blockIdx.x;           // (b*H + h)*NB + u
  int u = blk & (NB_ - 1);
  int bh = blk >> 5;
  int h = bh & (H_ - 1);
  bool rot = (h >= HH_);
  int tid = threadIdx.x;
  int rq = tid >> 5;              // 0..7
  int l  = tid & 31;              // 0..31
  int d0 = l * 4;
  const float* kb = k + (size_t)bh * T_ * DH_;

  float4 s = {0.f, 0.f, 0.f, 0.f};
  float4 first = {0.f, 0.f, 0.f, 0.f};
  #pragma unroll
  for (int it = 0; it < 16; ++it) {
    int i = it * 8 + rq;
    int t = u * BSZ_ + i;
    if (rot) t = (t + (BSZ_ - 1)) & (T_ - 1);
    float4 a = *(const float4*)(kb + (size_t)t * DH_ + d0);
    s.x += a.x; s.y += a.y; s.z += a.z; s.w += a.w;
    if (it == 0 && rq == 0) first = a;
  }
  red[rq][l] = s;
  __syncthreads();
  if (rq == 0) {
    float4 acc = {0.f, 0.f, 0.f, 0.f};
    #pragma unroll
    for (int j = 0; j < 8; ++j) {
      float4 a = red[j][l];
      acc.x += a.x; acc.y += a.y; acc.z += a.z; acc.w += a.w;
    }
    *(float4*)(bucketsum + (size_t)blk * DH_ + d0) = acc;
    *(float4*)(firstrow  + (size_t)blk * DH_ + d0) = first;
  }
}

// ---------------- Kernel A2: routing matrix R -> (scale, idx) packed float2 -------------
__global__ __launch_bounds__(256)
void k_routing(const float* __restrict__ W,
               const float* __restrict__ bucketsum,
               const float* __restrict__ firstrow,
               float2* __restrict__ scIdx) {
  __shared__ float Wl[2 * DH_ * NB_];      // [e][v] row-major, 8192 floats
  __shared__ float Xl[NB_][2 * DH_ + 1];   // padded
  __shared__ float Rl[NB_][36];            // 36-float rows: 16B aligned
  int bh = blockIdx.x;
  int h = bh & (H_ - 1);
  int tid = threadIdx.x;                   // 256 threads

  const float4* Wg = (const float4*)(W + (size_t)h * 2 * DH_ * NB_);
  #pragma unroll
  for (int rep = 0; rep < 8; ++rep)
    ((float4*)Wl)[tid + rep * 256] = Wg[tid + rep * 256];

  if (tid < DH_) {
    int d = tid;
    float S = 0.f;
    for (int u = 0; u < NB_; ++u) {
      float fr = firstrow [((size_t)bh * NB_ + u) * DH_ + d];
      float bs = bucketsum[((size_t)bh * NB_ + u) * DH_ + d];
      Xl[u][d]        = (S + fr) / (float)(u * BSZ_ + 1);
      Xl[u][DH_ + d]  = fr;
      S += bs;
    }
  }
  __syncthreads();

  {
    int u = tid >> 3;
    int vg = tid & 7;
    float4 racc = {0.f, 0.f, 0.f, 0.f};
    for (int e = 0; e < 2 * DH_; ++e) {
      float xv = Xl[u][e];
      float4 wv = *(const float4*)(Wl + e * NB_ + vg * 4);
      racc.x += xv * wv.x; racc.y += xv * wv.y;
      racc.z += xv * wv.z; racc.w += xv * wv.w;
    }
    racc.x = (racc.x > 0.f) ? racc.x : 0.01f * racc.x;
    racc.y = (racc.y > 0.f) ? racc.y : 0.01f * racc.y;
    racc.z = (racc.z > 0.f) ? racc.z : 0.01f * racc.z;
    racc.w = (racc.w > 0.f) ? racc.w : 0.01f * racc.w;
    *(float4*)(&Rl[u][vg * 4]) = racc;
  }
  __syncthreads();

  if (tid < NB_) {
    int u = tid;
    float m = -3.4e38f;
    float r[NB_];
    #pragma unroll
    for (int v = 0; v < NB_; ++v) { r[v] = Rl[u][v]; m = fmaxf(m, r[v]); }
    float Z = 0.f;
    #pragma unroll
    for (int v = 0; v < NB_; ++v) Z += expf(r[v] - m);
    float best = -3.4e38f; int bi = 0;
    for (int v = 0; v < u; ++v) {        // tril(-1): only v < u survive
      if (r[v] > best) { best = r[v]; bi = v; }
    }
    float sc = (u == 0) ? 0.f : expf(best - m) / Z;
    int  idx = (u == 0) ? 0 : bi;
    scIdx[bh * NB_ + u] = make_float2(sc, __int_as_float(idx));
  }
}

// ---------------- Kernel B: R6 structure + rep-granularity V pipeline ------------------
// RA 32KB: K1(src) -> VT1(src). RB 32KB: K2(own) -> VT2(own).
// V staged one rep (16 regs) at a time so in-flight V never exceeds free headroom
// while acc (64 regs) is live. Issue points: V1.r0 pre-S2, V1.r1 under max-pass,
// V2.r0 under exp/pack, V2.r1 last.
__global__ __launch_bounds__(512, 4)
void k_attn(const float* __restrict__ q, const float* __restrict__ k,
            const float* __restrict__ v, const float2* __restrict__ scIdx,
            float* __restrict__ out) {
  __shared__ __align__(16) unsigned short RA[128 * 128];   // 32KB
  __shared__ __align__(16) unsigned short RB[128 * 128];   // 32KB

  int blk0 = blockIdx.x;
  int blk  = ((blk0 & 7) << 7) | (blk0 >> 3);  // XCD-chunked swizzle (1024 = 8*128)
  int u  = blk & (NB_ - 1);
  int bh = blk >> 5;
  int h  = bh & (H_ - 1);
  bool rot = (h >= HH_);
  float2 si = scIdx[bh * NB_ + u];
  float sc = si.x;
  int  src = __float_as_int(si.y);
  const size_t base = (size_t)bh * T_ * DH_;

  int tid  = threadIdx.x;
  int lane = tid & 63;
  int w    = tid >> 6;        // wave 0..7, owns q-rows [16w, 16w+16)
  int g    = lane >> 4;       // 0..3
  int c    = lane & 15;       // 0..15

  // ---- Q fragments (B-operand: col = c -> i = 16w + c) ----
  short8 qf[4];
  {
    int t = u * BSZ_ + 16 * w + c;
    if (rot) t = (t + (BSZ_ - 1)) & (T_ - 1);
    const float* qrow = q + base + (size_t)t * DH_;
    #pragma unroll
    for (int kt = 0; kt < 4; ++kt) {
      f32x4 a = *(const f32x4*)(qrow + kt * 32 + g * 8);
      f32x4 b = *(const f32x4*)(qrow + kt * 32 + g * 8 + 4);
      u32x4 tt;
      tt.x = cvt_pk_bf16(a[0], a[1]);
      tt.y = cvt_pk_bf16(a[2], a[3]);
      tt.z = cvt_pk_bf16(b[0], b[1]);
      tt.w = cvt_pk_bf16(b[2], b[3]);
      qf[kt] = __builtin_bit_cast(short8, tt);
    }
  }

  // ---- Stage K halves (pure copy-convert): K1->RA, K2->RB ----
  #pragma unroll
  for (int rep = 0; rep < 16; ++rep) {
    int chunk = tid + rep * 512;          // 8192 chunks of 4 floats
    int jr = chunk >> 5;                  // 0..255
    int c0 = (chunk & 31) * 4;
    int t = (jr < BSZ_) ? (src * BSZ_ + jr) : (u * BSZ_ + (jr - BSZ_));
    if (rot) t = (t + (BSZ_ - 1)) & (T_ - 1);
    f32x4 a = *(const f32x4*)(k + base + (size_t)t * DH_ + c0);
    uint2 wv;
    wv.x = cvt_pk_bf16(a[0], a[1]);
    wv.y = cvt_pk_bf16(a[2], a[3]);
    unsigned short* Rg = (jr < BSZ_) ? RA : RB;
    int row = jr & 127;
    *(uint2*)((char*)Rg + row * 256 + ((c0 * 2) ^ ((row & 15) << 4))) = wv;
  }
  __syncthreads();   // S1

  // ---- V rep-level issue/commit (16 regs in flight max while acc is live) ----
  // Column permute within each 32-j block: jc = (j&~31) | 8*((j>>2)&3) | 4*((j>>4)&1) | (j&3)
  auto v_issue1 = [&](int sb, int rep, f32x4* rr) {
    int j0 = ((tid >> 5) + rep * 16) * 4;
    int d0 = (tid & 31) * 4;
    #pragma unroll
    for (int jj = 0; jj < 4; ++jj) {
      int t = sb * BSZ_ + j0 + jj;
      if (rot) t = (t + (BSZ_ - 1)) & (T_ - 1);
      rr[jj] = *(const f32x4*)(v + base + (size_t)t * DH_ + d0);
    }
  };
  auto v_commit1 = [&](int rep, const f32x4* rr, unsigned short* Rg) {
    int j0 = ((tid >> 5) + rep * 16) * 4;
    int jc0 = (j0 & ~31) | (((j0 >> 2) & 3) << 3) | (((j0 >> 4) & 1) << 2);
    int d0 = (tid & 31) * 4;
    #pragma unroll
    for (int m = 0; m < 4; ++m) {
      uint2 wv;
      wv.x = cvt_pk_bf16(rr[0][m], rr[1][m]);
      wv.y = cvt_pk_bf16(rr[2][m], rr[3][m]);
      int row = d0 + m;
      *(uint2*)((char*)Rg + row * 256 + ((jc0 * 2) ^ ((row & 15) << 4))) = wv;
    }
  };

  // ---- QK^T swapped: acc[jt][r] = S[j = 16jt+4g+r][i = 16w+c] ----
  f32x4 acc[16];
  #pragma unroll
  for (int jt = 0; jt < 16; ++jt) acc[jt] = f32x4{0.f, 0.f, 0.f, 0.f};

  __builtin_amdgcn_s_setprio(1);
  #pragma unroll
  for (int kt = 0; kt < 4; ++kt) {
    #pragma unroll
    for (int jt = 0; jt < 16; ++jt) {
      const unsigned short* Rg = (jt < 8) ? RA : RB;
      int row = (jt & 7) * 16 + c;
      short8 bfr = *(const short8*)((const char*)Rg + row * 256 + ((kt * 64 + g * 16) ^ ((row & 15) << 4)));
      acc[jt] = __builtin_amdgcn_mfma_f32_16x16x32_bf16(bfr, qf[kt], acc[jt], 0, 0, 0);
    }
  }
  __builtin_amdgcn_s_setprio(0);

  f32x4 va[4];
  v_issue1(src, 0, va);        // V1.rep0 in flight across S2 (acc 64 + 16 regs: safe)

  __syncthreads();   // S2 (K reads done; RA/RB free)

  v_commit1(0, va, RA);        // VT1 rows j 0..63 -> RA
  f32x4 vb[4];
  v_issue1(src, 1, vb);        // V1.rep1 in flight under the max pass

  // ---- mask + softmax, fully lane-local row (i = 16w + c) ----
  const bool lastrot = rot && (u == NB_ - 1);
  const float LOG2E = 1.44269504f;
  float scale1 = 0.03125f * LOG2E * sc;   // cols j<128 (src bucket)
  float scale2 = 0.03125f * LOG2E;        // cols j>=128 (own bucket)
  const int i = 16 * w + c;
  const bool killLow = lastrot && (i > 0);

  float mx = -3.4e38f;
  #pragma unroll
  for (int jt = 0; jt < 16; ++jt) {
    #pragma unroll
    for (int r = 0; r < 4; ++r) {
      float s = acc[jt][r] * ((jt < 8) ? scale1 : scale2);
      bool vis;
      if (jt < 8) {
        vis = !killLow;
      } else {
        int jb = 16 * (jt - 8) + 4 * g + r;
        vis = (i >= jb);
        if (jt == 8) vis = vis && !(killLow && (g == 0) && (r == 0));
      }
      s = vis ? s : -3.4e38f;
      acc[jt][r] = s;
      mx = fmaxf(mx, s);
    }
  }
  mx = fmaxf(mx, __shfl_xor(mx, 16));
  mx = fmaxf(mx, __shfl_xor(mx, 32));

  v_commit1(1, vb, RA);        // VT1 rows j 64..127 -> RA (loads arrived during max pass)

  float zs = 0.f;
  #pragma unroll
  for (int jt = 0; jt < 16; ++jt) {
    #pragma unroll
    for (int r = 0; r < 4; ++r) {
      float p = exp2f(acc[jt][r] - mx);
      acc[jt][r] = p;
      zs += p;
    }
  }
  zs += __shfl_xor(zs, 16);
  zs += __shfl_xor(zs, 32);
  float rz = 1.f / zs;
  float rzs = rz * sc;                   // P cols j<128 carry sc into PV

  f32x4 vc[4];
  v_issue1(u, 0, vc);          // V2.rep0 in flight under normalize+pack

  #pragma unroll
  for (int jt = 0; jt < 16; ++jt) {
    #pragma unroll
    for (int r = 0; r < 4; ++r) acc[jt][r] *= (jt < 8) ? rzs : rz;
  }

  // ---- P A-frags: pure register repack (matches VT column permute); acc dies here ----
  short8 pa[8];
  #pragma unroll
  for (int m = 0; m < 8; ++m) {
    u32x4 tt;
    tt.x = cvt_pk_bf16(acc[2 * m][0],     acc[2 * m][1]);
    tt.y = cvt_pk_bf16(acc[2 * m][2],     acc[2 * m][3]);
    tt.z = cvt_pk_bf16(acc[2 * m + 1][0], acc[2 * m + 1][1]);
    tt.w = cvt_pk_bf16(acc[2 * m + 1][2], acc[2 * m + 1][3]);
    pa[m] = __builtin_bit_cast(short8, tt);
  }

  v_commit1(0, vc, RB);        // VT2 rows j 0..63 -> RB
  f32x4 vd[4];
  v_issue1(u, 1, vd);          // V2.rep1 (acc dead: plenty of headroom)
  v_commit1(1, vd, RB);        // VT2 rows j 64..127 -> RB
  __syncthreads();   // S3

  // ---- PV: one contiguous 64-MFMA cluster, P from registers ----
  f32x4 o[8];
  #pragma unroll
  for (int nt = 0; nt < 8; ++nt) o[nt] = f32x4{0.f, 0.f, 0.f, 0.f};

  __builtin_amdgcn_s_setprio(1);
  #pragma unroll
  for (int m = 0; m < 8; ++m) {
    const unsigned short* Rg = (m < 4) ? RA : RB;
    int mloc = m & 3;
    #pragma unroll
    for (int nt = 0; nt < 8; ++nt) {
      int vrow = nt * 16 + c;
      short8 vb2 = *(const short8*)((const char*)Rg + vrow * 256 + ((mloc * 64 + g * 16) ^ ((vrow & 15) << 4)));
      o[nt] = __builtin_amdgcn_mfma_f32_16x16x32_bf16(pa[m], vb2, o[nt], 0, 0, 0);
    }
  }
  __builtin_amdgcn_s_setprio(0);

  // ---- store (undo rotation); o[nt][r] = O[i=16w+4g+r][d=16nt+c] ----
  #pragma unroll
  for (int r = 0; r < 4; ++r) {
    int il = 4 * g + r;
    int t = u * BSZ_ + 16 * w + il;
    if (rot) t = (t + (BSZ_ - 1)) & (T_ - 1);
    float* orow = out + base + (size_t)t * DH_;
    #pragma unroll
    for (int nt = 0; nt < 8; ++nt) {
      orow[nt * 16 + c] = o[nt][r];
    }
  }
}

extern "C" void kernel_launch(void* const* d_in, const int* in_sizes, int n_in,
                              void* d_out, int out_size, void* d_ws, size_t ws_size,
                              hipStream_t stream) {
  const float* q = (const float*)d_in[0];
  const float* k = (const float*)d_in[1];
  const float* v = (const float*)d_in[2];
  const float* W = (const float*)d_in[3];
  float* out = (float*)d_out;

  float*  bucketsum = (float*)d_ws;                 // 131072 floats
  float*  firstrow  = bucketsum + 131072;           // 131072 floats
  float2* scIdx     = (float2*)(firstrow + 131072); // 1024 float2

  k_bucket_sums<<<BH_ * NB_, 256, 0, stream>>>(k, bucketsum, firstrow);
  k_routing<<<BH_, 256, 0, stream>>>(W, bucketsum, firstrow, scIdx);
  k_attn<<<BH_ * NB_, 512, 0, stream>>>(q, k, v, scIdx, out);
}

// Round 11
// 75.700 us; speedup vs baseline: 1.4513x; 1.2210x over previous
//
#include <hip/hip_runtime.h>

// Problem constants
constexpr int T_    = 4096;
constexpr int DH_   = 128;
constexpr int NB_   = 32;    // buckets
constexpr int BSZ_  = 128;   // bucket size
constexpr int HH_   = 4;     // H/2 (rotated heads start here)
constexpr int H_    = 8;
constexpr int BH_   = 32;    // B*H

typedef __attribute__((ext_vector_type(8))) short short8;
typedef __attribute__((ext_vector_type(4))) float f32x4;
typedef __attribute__((ext_vector_type(4))) unsigned int u32x4;

__device__ __forceinline__ unsigned int cvt_pk_bf16(float lo, float hi) {
  unsigned int r;
  asm("v_cvt_pk_bf16_f32 %0, %1, %2" : "=v"(r) : "v"(lo), "v"(hi));
  return r;
}

// ---------------- Kernel A1: per-bucket column sums + first row of each bucket ----------
__global__ __launch_bounds__(256)
void k_bucket_sums(const float* __restrict__ k,
                   float* __restrict__ bucketsum,
                   float* __restrict__ firstrow) {
  __shared__ float4 red[8][32];
  int blk = blockIdx.x;           // (b*H + h)*NB + u
  int u = blk & (NB_ - 1);
  int bh = blk >> 5;
  int h = bh & (H_ - 1);
  bool rot = (h >= HH_);
  int tid = threadIdx.x;
  int rq = tid >> 5;              // 0..7
  int l  = tid & 31;              // 0..31
  int d0 = l * 4;
  const float* kb = k + (size_t)bh * T_ * DH_;

  float4 s = {0.f, 0.f, 0.f, 0.f};
  float4 first = {0.f, 0.f, 0.f, 0.f};
  #pragma unroll
  for (int it = 0; it < 16; ++it) {
    int i = it * 8 + rq;
    int t = u * BSZ_ + i;
    if (rot) t = (t + (BSZ_ - 1)) & (T_ - 1);
    float4 a = *(const float4*)(kb + (size_t)t * DH_ + d0);
    s.x += a.x; s.y += a.y; s.z += a.z; s.w += a.w;
    if (it == 0 && rq == 0) first = a;
  }
  red[rq][l] = s;
  __syncthreads();
  if (rq == 0) {
    float4 acc = {0.f, 0.f, 0.f, 0.f};
    #pragma unroll
    for (int j = 0; j < 8; ++j) {
      float4 a = red[j][l];
      acc.x += a.x; acc.y += a.y; acc.z += a.z; acc.w += a.w;
    }
    *(float4*)(bucketsum + (size_t)blk * DH_ + d0) = acc;
    *(float4*)(firstrow  + (size_t)blk * DH_ + d0) = first;
  }
}

// ---------------- Kernel A2: routing matrix R -> (scale, idx) packed float2 -------------
__global__ __launch_bounds__(256)
void k_routing(const float* __restrict__ W,
               const float* __restrict__ bucketsum,
               const float* __restrict__ firstrow,
               float2* __restrict__ scIdx) {
  __shared__ float Wl[2 * DH_ * NB_];      // [e][v] row-major, 8192 floats
  __shared__ float Xl[NB_][2 * DH_ + 1];   // padded
  __shared__ float Rl[NB_][36];            // 36-float rows: 16B aligned
  int bh = blockIdx.x;
  int h = bh & (H_ - 1);
  int tid = threadIdx.x;                   // 256 threads

  const float4* Wg = (const float4*)(W + (size_t)h * 2 * DH_ * NB_);
  #pragma unroll
  for (int rep = 0; rep < 8; ++rep)
    ((float4*)Wl)[tid + rep * 256] = Wg[tid + rep * 256];

  if (tid < DH_) {
    int d = tid;
    float S = 0.f;
    for (int u = 0; u < NB_; ++u) {
      float fr = firstrow [((size_t)bh * NB_ + u) * DH_ + d];
      float bs = bucketsum[((size_t)bh * NB_ + u) * DH_ + d];
      Xl[u][d]        = (S + fr) / (float)(u * BSZ_ + 1);
      Xl[u][DH_ + d]  = fr;
      S += bs;
    }
  }
  __syncthreads();

  {
    int u = tid >> 3;
    int vg = tid & 7;
    float4 racc = {0.f, 0.f, 0.f, 0.f};
    for (int e = 0; e < 2 * DH_; ++e) {
      float xv = Xl[u][e];
      float4 wv = *(const float4*)(Wl + e * NB_ + vg * 4);
      racc.x += xv * wv.x; racc.y += xv * wv.y;
      racc.z += xv * wv.z; racc.w += xv * wv.w;
    }
    racc.x = (racc.x > 0.f) ? racc.x : 0.01f * racc.x;
    racc.y = (racc.y > 0.f) ? racc.y : 0.01f * racc.y;
    racc.z = (racc.z > 0.f) ? racc.z : 0.01f * racc.z;
    racc.w = (racc.w > 0.f) ? racc.w : 0.01f * racc.w;
    *(float4*)(&Rl[u][vg * 4]) = racc;
  }
  __syncthreads();

  if (tid < NB_) {
    int u = tid;
    float m = -3.4e38f;
    float r[NB_];
    #pragma unroll
    for (int v = 0; v < NB_; ++v) { r[v] = Rl[u][v]; m = fmaxf(m, r[v]); }
    float Z = 0.f;
    #pragma unroll
    for (int v = 0; v < NB_; ++v) Z += expf(r[v] - m);
    float best = -3.4e38f; int bi = 0;
    for (int v = 0; v < u; ++v) {        // tril(-1): only v < u survive
      if (r[v] > best) { best = r[v]; bi = v; }
    }
    float sc = (u == 0) ? 0.f : expf(best - m) / Z;
    int  idx = (u == 0) ? 0 : bi;
    scIdx[bh * NB_ + u] = make_float2(sc, __int_as_float(idx));
  }
}

// ---------------- Kernel B: R6 structure + causal tile skipping ------------------------
// RA 32KB: K1(src) -> VT1(src). RB 32KB: K2(own) -> VT2(own).
// Wave w (rows i in [16w,16w+16)): own-half tile jtb fully masked iff jtb > w ->
// skip its QK MFMA/reads, softmax passes, pack, and PV (mloc > w>>1). Skipped acc
// stays zero -> packs as P=0 (bit-identical to masked path).
__global__ __launch_bounds__(512, 4)
void k_attn(const float* __restrict__ q, const float* __restrict__ k,
            const float* __restrict__ v, const float2* __restrict__ scIdx,
            float* __restrict__ out) {
  __shared__ __align__(16) unsigned short RA[128 * 128];   // 32KB
  __shared__ __align__(16) unsigned short RB[128 * 128];   // 32KB

  int blk0 = blockIdx.x;
  int blk  = ((blk0 & 7) << 7) | (blk0 >> 3);  // XCD-chunked swizzle (1024 = 8*128)
  int u  = blk & (NB_ - 1);
  int bh = blk >> 5;
  int h  = bh & (H_ - 1);
  bool rot = (h >= HH_);
  float2 si = scIdx[bh * NB_ + u];
  float sc = si.x;
  int  src = __float_as_int(si.y);
  const size_t base = (size_t)bh * T_ * DH_;

  int tid  = threadIdx.x;
  int lane = tid & 63;
  int w    = tid >> 6;        // wave 0..7, owns q-rows [16w, 16w+16)
  int g    = lane >> 4;       // 0..3
  int c    = lane & 15;       // 0..15

  // ---- Q fragments (B-operand: col = c -> i = 16w + c) ----
  short8 qf[4];
  {
    int t = u * BSZ_ + 16 * w + c;
    if (rot) t = (t + (BSZ_ - 1)) & (T_ - 1);
    const float* qrow = q + base + (size_t)t * DH_;
    #pragma unroll
    for (int kt = 0; kt < 4; ++kt) {
      f32x4 a = *(const f32x4*)(qrow + kt * 32 + g * 8);
      f32x4 b = *(const f32x4*)(qrow + kt * 32 + g * 8 + 4);
      u32x4 tt;
      tt.x = cvt_pk_bf16(a[0], a[1]);
      tt.y = cvt_pk_bf16(a[2], a[3]);
      tt.z = cvt_pk_bf16(b[0], b[1]);
      tt.w = cvt_pk_bf16(b[2], b[3]);
      qf[kt] = __builtin_bit_cast(short8, tt);
    }
  }

  // ---- Stage K halves (pure copy-convert): K1->RA, K2->RB ----
  #pragma unroll
  for (int rep = 0; rep < 16; ++rep) {
    int chunk = tid + rep * 512;          // 8192 chunks of 4 floats
    int jr = chunk >> 5;                  // 0..255
    int c0 = (chunk & 31) * 4;
    int t = (jr < BSZ_) ? (src * BSZ_ + jr) : (u * BSZ_ + (jr - BSZ_));
    if (rot) t = (t + (BSZ_ - 1)) & (T_ - 1);
    f32x4 a = *(const f32x4*)(k + base + (size_t)t * DH_ + c0);
    uint2 wv;
    wv.x = cvt_pk_bf16(a[0], a[1]);
    wv.y = cvt_pk_bf16(a[2], a[3]);
    unsigned short* Rg = (jr < BSZ_) ? RA : RB;
    int row = jr & 127;
    *(uint2*)((char*)Rg + row * 256 + ((c0 * 2) ^ ((row & 15) << 4))) = wv;
  }
  __syncthreads();   // S1

  // ---- VT staging: load -> convert -> commit immediately (transient regs only) ----
  // Column permute within each 32-j block: jc = (j&~31) | 8*((j>>2)&3) | 4*((j>>4)&1) | (j&3)
  auto vt_stage = [&](int sb, unsigned short* Rg) {
    #pragma unroll
    for (int rep = 0; rep < 2; ++rep) {
      int j0 = ((tid >> 5) + rep * 16) * 4;
      int jc0 = (j0 & ~31) | (((j0 >> 2) & 3) << 3) | (((j0 >> 4) & 1) << 2);
      int d0 = (tid & 31) * 4;
      f32x4 rr[4];
      #pragma unroll
      for (int jj = 0; jj < 4; ++jj) {
        int t = sb * BSZ_ + j0 + jj;
        if (rot) t = (t + (BSZ_ - 1)) & (T_ - 1);
        rr[jj] = *(const f32x4*)(v + base + (size_t)t * DH_ + d0);
      }
      #pragma unroll
      for (int m = 0; m < 4; ++m) {
        uint2 wv;
        wv.x = cvt_pk_bf16(rr[0][m], rr[1][m]);
        wv.y = cvt_pk_bf16(rr[2][m], rr[3][m]);
        int row = d0 + m;
        *(uint2*)((char*)Rg + row * 256 + ((jc0 * 2) ^ ((row & 15) << 4))) = wv;
      }
    }
  };

  const bool lastrot = rot && (u == NB_ - 1);
  const float LOG2E = 1.44269504f;
  const float scale1 = 0.03125f * LOG2E * sc;   // cols j<128 (src bucket)
  const float scale2 = 0.03125f * LOG2E;        // cols j>=128 (own bucket)
  const int i = 16 * w + c;
  const bool killLow = lastrot && (i > 0);

  // ---- QK^T swapped: acc[jt][r] = S[j = 16jt+4g+r][i = 16w+c]; skip jt > 8+w ----
  f32x4 acc[16];
  #pragma unroll
  for (int jt = 0; jt < 16; ++jt) acc[jt] = f32x4{0.f, 0.f, 0.f, 0.f};

  __builtin_amdgcn_s_setprio(1);
  #pragma unroll
  for (int kt = 0; kt < 4; ++kt) {
    #pragma unroll
    for (int jt = 0; jt < 16; ++jt) {
      if (jt <= 8 + w) {
        const unsigned short* Rg = (jt < 8) ? RA : RB;
        int row = (jt & 7) * 16 + c;
        short8 bfr = *(const short8*)((const char*)Rg + row * 256 + ((kt * 64 + g * 16) ^ ((row & 15) << 4)));
        acc[jt] = __builtin_amdgcn_mfma_f32_16x16x32_bf16(bfr, qf[kt], acc[jt], 0, 0, 0);
      }
    }
  }
  __builtin_amdgcn_s_setprio(0);

  __syncthreads();   // S2 (K reads done; RA/RB free)

  vt_stage(src, RA);           // VT1 -> RA; loads hide under softmax

  // ---- mask + softmax, fully lane-local row (i = 16w + c); skipped tiles stay 0 ----
  float mx = -3.4e38f;
  #pragma unroll
  for (int jt = 0; jt < 16; ++jt) {
    if (jt <= 8 + w) {
      #pragma unroll
      for (int r = 0; r < 4; ++r) {
        float s = acc[jt][r] * ((jt < 8) ? scale1 : scale2);
        bool vis;
        if (jt < 8) {
          vis = !killLow;
        } else {
          int jb = 16 * (jt - 8) + 4 * g + r;
          vis = (i >= jb);
          if (jt == 8) vis = vis && !(killLow && (g == 0) && (r == 0));
        }
        s = vis ? s : -3.4e38f;
        acc[jt][r] = s;
        mx = fmaxf(mx, s);
      }
    }
  }
  mx = fmaxf(mx, __shfl_xor(mx, 16));
  mx = fmaxf(mx, __shfl_xor(mx, 32));
  float zs = 0.f;
  #pragma unroll
  for (int jt = 0; jt < 16; ++jt) {
    if (jt <= 8 + w) {
      #pragma unroll
      for (int r = 0; r < 4; ++r) {
        float p = exp2f(acc[jt][r] - mx);
        acc[jt][r] = p;
        zs += p;
      }
    }
  }
  zs += __shfl_xor(zs, 16);
  zs += __shfl_xor(zs, 32);
  float rz = 1.f / zs;
  float rzs = rz * sc;                   // P cols j<128 carry sc into PV

  vt_stage(u, RB);             // VT2 -> RB (loads overlap softmax tail / pack)

  // ---- P A-frags: register repack with f folded; skip fully-masked own-half m ----
  short8 pa[8];
  #pragma unroll
  for (int m = 0; m < 8; ++m) {
    if (m < 4 || (m - 4) <= (w >> 1)) {
      float fa = (m < 4) ? rzs : rz;     // jt = 2m, 2m+1 are both <8 iff m<4
      u32x4 tt;
      tt.x = cvt_pk_bf16(acc[2 * m][0] * fa,     acc[2 * m][1] * fa);
      tt.y = cvt_pk_bf16(acc[2 * m][2] * fa,     acc[2 * m][3] * fa);
      tt.z = cvt_pk_bf16(acc[2 * m + 1][0] * fa, acc[2 * m + 1][1] * fa);
      tt.w = cvt_pk_bf16(acc[2 * m + 1][2] * fa, acc[2 * m + 1][3] * fa);
      pa[m] = __builtin_bit_cast(short8, tt);
    }
  }
  __syncthreads();   // S3

  // ---- PV: P from registers; skip own-half m with all-zero P ----
  f32x4 o[8];
  #pragma unroll
  for (int nt = 0; nt < 8; ++nt) o[nt] = f32x4{0.f, 0.f, 0.f, 0.f};

  __builtin_amdgcn_s_setprio(1);
  #pragma unroll
  for (int m = 0; m < 8; ++m) {
    if (m < 4 || (m - 4) <= (w >> 1)) {
      const unsigned short* Rg = (m < 4) ? RA : RB;
      int mloc = m & 3;
      #pragma unroll
      for (int nt = 0; nt < 8; ++nt) {
        int vrow = nt * 16 + c;
        short8 vb = *(const short8*)((const char*)Rg + vrow * 256 + ((mloc * 64 + g * 16) ^ ((vrow & 15) << 4)));
        o[nt] = __builtin_amdgcn_mfma_f32_16x16x32_bf16(pa[m], vb, o[nt], 0, 0, 0);
      }
    }
  }
  __builtin_amdgcn_s_setprio(0);

  // ---- store (undo rotation); o[nt][r] = O[i=16w+4g+r][d=16nt+c] ----
  #pragma unroll
  for (int r = 0; r < 4; ++r) {
    int il = 4 * g + r;
    int t = u * BSZ_ + 16 * w + il;
    if (rot) t = (t + (BSZ_ - 1)) & (T_ - 1);
    float* orow = out + base + (size_t)t * DH_;
    #pragma unroll
    for (int nt = 0; nt < 8; ++nt) {
      orow[nt * 16 + c] = o[nt][r];
    }
  }
}

extern "C" void kernel_launch(void* const* d_in, const int* in_sizes, int n_in,
                              void* d_out, int out_size, void* d_ws, size_t ws_size,
                              hipStream_t stream) {
  const float* q = (const float*)d_in[0];
  const float* k = (const float*)d_in[1];
  const float* v = (const float*)d_in[2];
  const float* W = (const float*)d_in[3];
  float* out = (float*)d_out;

  float*  bucketsum = (float*)d_ws;                 // 131072 floats
  float*  firstrow  = bucketsum + 131072;           // 131072 floats
  float2* scIdx     = (float2*)(firstrow + 131072); // 1024 float2

  k_bucket_sums<<<BH_ * NB_, 256, 0, stream>>>(k, bucketsum, firstrow);
  k_routing<<<BH_, 256, 0, stream>>>(W, bucketsum, firstrow, scIdx);
  k_attn<<<BH_ * NB_, 512, 0, stream>>>(q, k, v, scIdx, out);
}

// Round 12
// 73.702 us; speedup vs baseline: 1.4907x; 1.0271x over previous
//
#include <hip/hip_runtime.h>

// Problem constants
constexpr int T_    = 4096;
constexpr int DH_   = 128;
constexpr int NB_   = 32;    // buckets
constexpr int BSZ_  = 128;   // bucket size
constexpr int HH_   = 4;     // H/2 (rotated heads start here)
constexpr int H_    = 8;
constexpr int BH_   = 32;    // B*H

typedef __attribute__((ext_vector_type(8))) short short8;
typedef __attribute__((ext_vector_type(4))) float f32x4;
typedef __attribute__((ext_vector_type(4))) unsigned int u32x4;

__device__ __forceinline__ unsigned int cvt_pk_bf16(float lo, float hi) {
  unsigned int r;
  asm("v_cvt_pk_bf16_f32 %0, %1, %2" : "=v"(r) : "v"(lo), "v"(hi));
  return r;
}

// ---------------- Kernel A1: per-bucket column sums + first row of each bucket ----------
__global__ __launch_bounds__(256)
void k_bucket_sums(const float* __restrict__ k,
                   float* __restrict__ bucketsum,
                   float* __restrict__ firstrow) {
  __shared__ float4 red[8][32];
  int blk = blockIdx.x;           // (b*H + h)*NB + u
  int u = blk & (NB_ - 1);
  int bh = blk >> 5;
  int h = bh & (H_ - 1);
  bool rot = (h >= HH_);
  int tid = threadIdx.x;
  int rq = tid >> 5;              // 0..7
  int l  = tid & 31;              // 0..31
  int d0 = l * 4;
  const float* kb = k + (size_t)bh * T_ * DH_;

  float4 s = {0.f, 0.f, 0.f, 0.f};
  float4 first = {0.f, 0.f, 0.f, 0.f};
  #pragma unroll
  for (int it = 0; it < 16; ++it) {
    int i = it * 8 + rq;
    int t = u * BSZ_ + i;
    if (rot) t = (t + (BSZ_ - 1)) & (T_ - 1);
    float4 a = *(const float4*)(kb + (size_t)t * DH_ + d0);
    s.x += a.x; s.y += a.y; s.z += a.z; s.w += a.w;
    if (it == 0 && rq == 0) first = a;
  }
  red[rq][l] = s;
  __syncthreads();
  if (rq == 0) {
    float4 acc = {0.f, 0.f, 0.f, 0.f};
    #pragma unroll
    for (int j = 0; j < 8; ++j) {
      float4 a = red[j][l];
      acc.x += a.x; acc.y += a.y; acc.z += a.z; acc.w += a.w;
    }
    *(float4*)(bucketsum + (size_t)blk * DH_ + d0) = acc;
    *(float4*)(firstrow  + (size_t)blk * DH_ + d0) = first;
  }
}

// ---------------- Kernel A2: routing matrix R -> (scale, idx) packed float2 -------------
__global__ __launch_bounds__(256)
void k_routing(const float* __restrict__ W,
               const float* __restrict__ bucketsum,
               const float* __restrict__ firstrow,
               float2* __restrict__ scIdx) {
  __shared__ float Wl[2 * DH_ * NB_];      // [e][v] row-major, 8192 floats
  __shared__ float Xl[NB_][2 * DH_ + 1];   // padded
  __shared__ float Rl[NB_][36];            // 36-float rows: 16B aligned
  int bh = blockIdx.x;
  int h = bh & (H_ - 1);
  int tid = threadIdx.x;                   // 256 threads

  const float4* Wg = (const float4*)(W + (size_t)h * 2 * DH_ * NB_);
  #pragma unroll
  for (int rep = 0; rep < 8; ++rep)
    ((float4*)Wl)[tid + rep * 256] = Wg[tid + rep * 256];

  if (tid < DH_) {
    int d = tid;
    float S = 0.f;
    for (int u = 0; u < NB_; ++u) {
      float fr = firstrow [((size_t)bh * NB_ + u) * DH_ + d];
      float bs = bucketsum[((size_t)bh * NB_ + u) * DH_ + d];
      Xl[u][d]        = (S + fr) / (float)(u * BSZ_ + 1);
      Xl[u][DH_ + d]  = fr;
      S += bs;
    }
  }
  __syncthreads();

  {
    int u = tid >> 3;
    int vg = tid & 7;
    float4 racc = {0.f, 0.f, 0.f, 0.f};
    for (int e = 0; e < 2 * DH_; ++e) {
      float xv = Xl[u][e];
      float4 wv = *(const float4*)(Wl + e * NB_ + vg * 4);
      racc.x += xv * wv.x; racc.y += xv * wv.y;
      racc.z += xv * wv.z; racc.w += xv * wv.w;
    }
    racc.x = (racc.x > 0.f) ? racc.x : 0.01f * racc.x;
    racc.y = (racc.y > 0.f) ? racc.y : 0.01f * racc.y;
    racc.z = (racc.z > 0.f) ? racc.z : 0.01f * racc.z;
    racc.w = (racc.w > 0.f) ? racc.w : 0.01f * racc.w;
    *(float4*)(&Rl[u][vg * 4]) = racc;
  }
  __syncthreads();

  if (tid < NB_) {
    int u = tid;
    float m = -3.4e38f;
    float r[NB_];
    #pragma unroll
    for (int v = 0; v < NB_; ++v) { r[v] = Rl[u][v]; m = fmaxf(m, r[v]); }
    float Z = 0.f;
    #pragma unroll
    for (int v = 0; v < NB_; ++v) Z += expf(r[v] - m);
    float best = -3.4e38f; int bi = 0;
    for (int v = 0; v < u; ++v) {        // tril(-1): only v < u survive
      if (r[v] > best) { best = r[v]; bi = v; }
    }
    float sc = (u == 0) ? 0.f : expf(best - m) / Z;
    int  idx = (u == 0) ? 0 : bi;
    scIdx[bh * NB_ + u] = make_float2(sc, __int_as_float(idx));
  }
}

// ---------------- Kernel B: R11 + sc folded into K1/V1 staging + acc reuse for o -------
// RA 32KB: K1(sc*src) -> VT1(sc*src). RB 32KB: K2(own) -> VT2(own).
// Q carries d^-0.5*log2e; softmax is pure max/exp/sum with single rz.
// PV accumulates into acc[0..7] (dead after pack) to cut peak AGPRs 96->64.
__global__ __launch_bounds__(512, 4)
void k_attn(const float* __restrict__ q, const float* __restrict__ k,
            const float* __restrict__ v, const float2* __restrict__ scIdx,
            float* __restrict__ out) {
  __shared__ __align__(16) unsigned short RA[128 * 128];   // 32KB
  __shared__ __align__(16) unsigned short RB[128 * 128];   // 32KB

  int blk0 = blockIdx.x;
  int blk  = ((blk0 & 7) << 7) | (blk0 >> 3);  // XCD-chunked swizzle (1024 = 8*128)
  int u  = blk & (NB_ - 1);
  int bh = blk >> 5;
  int h  = bh & (H_ - 1);
  bool rot = (h >= HH_);
  float2 si = scIdx[bh * NB_ + u];
  float sc = si.x;
  int  src = __float_as_int(si.y);
  const size_t base = (size_t)bh * T_ * DH_;

  int tid  = threadIdx.x;
  int lane = tid & 63;
  int w    = tid >> 6;        // wave 0..7, owns q-rows [16w, 16w+16)
  int g    = lane >> 4;       // 0..3
  int c    = lane & 15;       // 0..15

  const float QSCALE = 0.03125f * 1.44269504f;   // d^-0.5 * log2e folded into Q

  // ---- Q fragments (B-operand: col = c -> i = 16w + c), pre-scaled ----
  short8 qf[4];
  {
    int t = u * BSZ_ + 16 * w + c;
    if (rot) t = (t + (BSZ_ - 1)) & (T_ - 1);
    const float* qrow = q + base + (size_t)t * DH_;
    #pragma unroll
    for (int kt = 0; kt < 4; ++kt) {
      f32x4 a = *(const f32x4*)(qrow + kt * 32 + g * 8) * QSCALE;
      f32x4 b = *(const f32x4*)(qrow + kt * 32 + g * 8 + 4) * QSCALE;
      u32x4 tt;
      tt.x = cvt_pk_bf16(a[0], a[1]);
      tt.y = cvt_pk_bf16(a[2], a[3]);
      tt.z = cvt_pk_bf16(b[0], b[1]);
      tt.w = cvt_pk_bf16(b[2], b[3]);
      qf[kt] = __builtin_bit_cast(short8, tt);
    }
  }

  // ---- Stage K halves: K1 = sc*k[src] -> RA, K2 = k[u] -> RB ----
  #pragma unroll
  for (int rep = 0; rep < 16; ++rep) {
    int chunk = tid + rep * 512;          // 8192 chunks of 4 floats
    int jr = chunk >> 5;                  // 0..255
    int c0 = (chunk & 31) * 4;
    int t; float mul;
    if (jr < BSZ_) { t = src * BSZ_ + jr;         mul = sc;  }
    else           { t = u  * BSZ_ + (jr - BSZ_); mul = 1.f; }
    if (rot) t = (t + (BSZ_ - 1)) & (T_ - 1);
    f32x4 a = *(const f32x4*)(k + base + (size_t)t * DH_ + c0) * mul;
    uint2 wv;
    wv.x = cvt_pk_bf16(a[0], a[1]);
    wv.y = cvt_pk_bf16(a[2], a[3]);
    unsigned short* Rg = (jr < BSZ_) ? RA : RB;
    int row = jr & 127;
    *(uint2*)((char*)Rg + row * 256 + ((c0 * 2) ^ ((row & 15) << 4))) = wv;
  }
  __syncthreads();   // S1

  // ---- VT staging: load -> convert -> commit immediately (transient regs only) ----
  // Column permute within each 32-j block: jc = (j&~31) | 8*((j>>2)&3) | 4*((j>>4)&1) | (j&3)
  auto vt_stage = [&](int sb, float mul, unsigned short* Rg) {
    #pragma unroll
    for (int rep = 0; rep < 2; ++rep) {
      int j0 = ((tid >> 5) + rep * 16) * 4;
      int jc0 = (j0 & ~31) | (((j0 >> 2) & 3) << 3) | (((j0 >> 4) & 1) << 2);
      int d0 = (tid & 31) * 4;
      f32x4 rr[4];
      #pragma unroll
      for (int jj = 0; jj < 4; ++jj) {
        int t = sb * BSZ_ + j0 + jj;
        if (rot) t = (t + (BSZ_ - 1)) & (T_ - 1);
        rr[jj] = *(const f32x4*)(v + base + (size_t)t * DH_ + d0) * mul;
      }
      #pragma unroll
      for (int m = 0; m < 4; ++m) {
        uint2 wv;
        wv.x = cvt_pk_bf16(rr[0][m], rr[1][m]);
        wv.y = cvt_pk_bf16(rr[2][m], rr[3][m]);
        int row = d0 + m;
        *(uint2*)((char*)Rg + row * 256 + ((jc0 * 2) ^ ((row & 15) << 4))) = wv;
      }
    }
  };

  const bool lastrot = rot && (u == NB_ - 1);
  const int i = 16 * w + c;
  const bool killLow = lastrot && (i > 0);

  // ---- QK^T swapped: acc[jt][r] = S[j = 16jt+4g+r][i = 16w+c]; skip jt > 8+w ----
  f32x4 acc[16];
  #pragma unroll
  for (int jt = 0; jt < 16; ++jt) acc[jt] = f32x4{0.f, 0.f, 0.f, 0.f};

  __builtin_amdgcn_s_setprio(1);
  #pragma unroll
  for (int kt = 0; kt < 4; ++kt) {
    #pragma unroll
    for (int jt = 0; jt < 16; ++jt) {
      if (jt <= 8 + w) {
        const unsigned short* Rg = (jt < 8) ? RA : RB;
        int row = (jt & 7) * 16 + c;
        short8 bfr = *(const short8*)((const char*)Rg + row * 256 + ((kt * 64 + g * 16) ^ ((row & 15) << 4)));
        acc[jt] = __builtin_amdgcn_mfma_f32_16x16x32_bf16(bfr, qf[kt], acc[jt], 0, 0, 0);
      }
    }
  }
  __builtin_amdgcn_s_setprio(0);

  __syncthreads();   // S2 (K reads done; RA/RB free)

  vt_stage(src, sc, RA);       // VT1 = sc*v[src] -> RA; loads hide under softmax

  // ---- mask + softmax (scores fully pre-scaled); skipped tiles stay 0 ----
  float mx = -3.4e38f;
  #pragma unroll
  for (int jt = 0; jt < 16; ++jt) {
    if (jt <= 8 + w) {
      #pragma unroll
      for (int r = 0; r < 4; ++r) {
        float s = acc[jt][r];
        bool vis;
        if (jt < 8) {
          vis = !killLow;
        } else {
          int jb = 16 * (jt - 8) + 4 * g + r;
          vis = (i >= jb);
          if (jt == 8) vis = vis && !(killLow && (g == 0) && (r == 0));
        }
        s = vis ? s : -3.4e38f;
        acc[jt][r] = s;
        mx = fmaxf(mx, s);
      }
    }
  }
  mx = fmaxf(mx, __shfl_xor(mx, 16));
  mx = fmaxf(mx, __shfl_xor(mx, 32));
  float zs = 0.f;
  #pragma unroll
  for (int jt = 0; jt < 16; ++jt) {
    if (jt <= 8 + w) {
      #pragma unroll
      for (int r = 0; r < 4; ++r) {
        float p = exp2f(acc[jt][r] - mx);
        acc[jt][r] = p;
        zs += p;
      }
    }
  }
  zs += __shfl_xor(zs, 16);
  zs += __shfl_xor(zs, 32);
  float rz = 1.f / zs;

  vt_stage(u, 1.f, RB);        // VT2 = v[u] -> RB (loads overlap softmax tail / pack)

  // ---- P A-frags: register repack, uniform rz; skip fully-masked own-half m ----
  short8 pa[8];
  #pragma unroll
  for (int m = 0; m < 8; ++m) {
    if (m < 4 || (m - 4) <= (w >> 1)) {
      u32x4 tt;
      tt.x = cvt_pk_bf16(acc[2 * m][0] * rz,     acc[2 * m][1] * rz);
      tt.y = cvt_pk_bf16(acc[2 * m][2] * rz,     acc[2 * m][3] * rz);
      tt.z = cvt_pk_bf16(acc[2 * m + 1][0] * rz, acc[2 * m + 1][1] * rz);
      tt.w = cvt_pk_bf16(acc[2 * m + 1][2] * rz, acc[2 * m + 1][3] * rz);
      pa[m] = __builtin_bit_cast(short8, tt);
    }
  }
  __syncthreads();   // S3

  // ---- PV: accumulate into acc[0..7] (acc dead after pack -> AGPR reuse) ----
  #pragma unroll
  for (int nt = 0; nt < 8; ++nt) acc[nt] = f32x4{0.f, 0.f, 0.f, 0.f};

  __builtin_amdgcn_s_setprio(1);
  #pragma unroll
  for (int m = 0; m < 8; ++m) {
    if (m < 4 || (m - 4) <= (w >> 1)) {
      const unsigned short* Rg = (m < 4) ? RA : RB;
      int mloc = m & 3;
      #pragma unroll
      for (int nt = 0; nt < 8; ++nt) {
        int vrow = nt * 16 + c;
        short8 vb = *(const short8*)((const char*)Rg + vrow * 256 + ((mloc * 64 + g * 16) ^ ((vrow & 15) << 4)));
        acc[nt] = __builtin_amdgcn_mfma_f32_16x16x32_bf16(pa[m], vb, acc[nt], 0, 0, 0);
      }
    }
  }
  __builtin_amdgcn_s_setprio(0);

  // ---- store (undo rotation); acc[nt][r] = O[i=16w+4g+r][d=16nt+c] ----
  #pragma unroll
  for (int r = 0; r < 4; ++r) {
    int il = 4 * g + r;
    int t = u * BSZ_ + 16 * w + il;
    if (rot) t = (t + (BSZ_ - 1)) & (T_ - 1);
    float* orow = out + base + (size_t)t * DH_;
    #pragma unroll
    for (int nt = 0; nt < 8; ++nt) {
      orow[nt * 16 + c] = acc[nt][r];
    }
  }
}

extern "C" void kernel_launch(void* const* d_in, const int* in_sizes, int n_in,
                              void* d_out, int out_size, void* d_ws, size_t ws_size,
                              hipStream_t stream) {
  const float* q = (const float*)d_in[0];
  const float* k = (const float*)d_in[1];
  const float* v = (const float*)d_in[2];
  const float* W = (const float*)d_in[3];
  float* out = (float*)d_out;

  float*  bucketsum = (float*)d_ws;                 // 131072 floats
  float*  firstrow  = bucketsum + 131072;           // 131072 floats
  float2* scIdx     = (float2*)(firstrow + 131072); // 1024 float2

  k_bucket_sums<<<BH_ * NB_, 256, 0, stream>>>(k, bucketsum, firstrow);
  k_routing<<<BH_, 256, 0, stream>>>(W, bucketsum, firstrow, scIdx);
  k_attn<<<BH_ * NB_, 512, 0, stream>>>(q, k, v, scIdx, out);
}